// Round 4
// baseline (155.943 us; speedup 1.0000x reference)
//
#include <hip/hip_runtime.h>
#include <hip/hip_bf16.h>
#include <cstdint>

typedef __attribute__((ext_vector_type(4))) float f32x4;
typedef __attribute__((ext_vector_type(8))) short bf16x8;

__device__ __forceinline__ ushort f2bf(float f) {
  unsigned u = __builtin_bit_cast(unsigned, f);
  u += 0x7fffu + ((u >> 16) & 1u);
  return (ushort)(u >> 16);
}
__device__ __forceinline__ float bf2f(ushort h) {
  unsigned u = ((unsigned)h) << 16;
  return __builtin_bit_cast(float, u);
}

__device__ __forceinline__ void gload_lds16(const ushort* g, ushort* l) {
  __builtin_amdgcn_global_load_lds(
      (const __attribute__((address_space(1))) unsigned int*)g,
      (__attribute__((address_space(3))) unsigned int*)l, 16, 0, 0);
}

__device__ __forceinline__ void hard_barrier() {
  __builtin_amdgcn_sched_barrier(0);
  __builtin_amdgcn_s_barrier();
  __builtin_amdgcn_sched_barrier(0);
}

template <int N>
__device__ __forceinline__ void wait_vm() {
  if constexpr (N == 0) asm volatile("s_waitcnt vmcnt(0)" ::: "memory");
  else if constexpr (N == 4) asm volatile("s_waitcnt vmcnt(4)" ::: "memory");
  else static_assert(N < 0, "unsupported vmcnt");
}

// ---------- kernel 0a: x fp32 -> bf16 ----------
__global__ __launch_bounds__(256) void cvt_x_kernel(const float4* __restrict__ x,
                                                    ushort4* __restrict__ xb, int n4) {
  int stride = gridDim.x * blockDim.x;
  for (int i = blockIdx.x * blockDim.x + threadIdx.x; i < n4; i += stride) {
    float4 f = x[i];
    ushort4 o;
    o.x = f2bf(f.x); o.y = f2bf(f.y); o.z = f2bf(f.z); o.w = f2bf(f.w);
    xb[i] = o;
  }
}

// ---------- kernel 0b: W_qkv [1024][1536] f32 -> Wt [1536][1024] bf16 ----------
__global__ __launch_bounds__(256) void transpose_w_kernel(const float* __restrict__ W,
                                                          ushort* __restrict__ Wt) {
  __shared__ float tile[32][33];
  int n0 = blockIdx.x * 32;
  int k0 = blockIdx.y * 32;
  int tx = threadIdx.x;  // 0..31
  int ty = threadIdx.y;  // 0..7
  #pragma unroll
  for (int p = 0; p < 4; ++p) {
    int k = k0 + ty + p * 8;
    tile[ty + p * 8][tx] = W[(size_t)k * 1536 + n0 + tx];
  }
  __syncthreads();
  #pragma unroll
  for (int p = 0; p < 4; ++p) {
    int n = n0 + ty + p * 8;
    Wt[(size_t)n * 1024 + k0 + tx] = f2bf(tile[tx][ty + p * 8]);
  }
}

// ============================================================================
// m201-style 8-phase 256x256 GEMM core. BK=64, 512 threads = 8 waves (2M x 4N),
// per-wave output 128x64 (MREP=8, NREP=4). LDS = 2 slots x 64KB = 128 KiB.
// Slot layout (ushorts): [A k0: 256x32 | A k1 | B k0 | B k1], each half 8192.
// K-tile = 4 half-tiles (Ak0,Bk0,Ak1,Bk1); stage = 2 global_load_lds/thread.
// 4 phases per K-tile: {ds_read frags; stage 1 half of tile t+1;
//   [vmcnt(4) at P1/P3]; barrier; setprio+16 MFMA}. vmcnt(4) = 2 halves in
// flight; never 0 in steady state. Stages always write slot (t+1)&1 != read
// slot (t&1) -> WAR safe; each read's data guaranteed by the vmcnt+barrier
// one phase earlier (verified by construction).
// Bank swizzle (rule #21: both-sides involution, linear gload_lds dest):
//   within a half: row r (64B), 4 x 16B slots; phys slot = logical ^ ((r>>1)&3)
//   staged by pre-swizzling the per-lane GLOBAL source column.
//   Read groups: lanes 0..7 hit 8 distinct 16B bank-groups -> 2-way (free).
// ============================================================================
template <int LDA, int LDB, int NT>
__device__ __forceinline__ void gemm_core8(const ushort* __restrict__ A,
                                           const ushort* __restrict__ Bt,
                                           int row0, int col0, f32x4 acc[8][4],
                                           ushort* lds) {
  const int tid = threadIdx.x;
  const int l = tid & 63;
  const int wid = tid >> 6;
  const int fr = l & 15, fq = l >> 4;
  const int wr = wid >> 2, wc = wid & 3;

  // ---- staging (pre-swizzled global source) ----
  const int srow = tid >> 2;                     // 0..127
  const int lam = (tid & 3) ^ ((tid >> 3) & 3);  // logical 16B slot
  const ushort* aG = A + (size_t)(row0 + srow) * LDA + lam * 8;
  const ushort* bG = Bt + (size_t)(col0 + srow) * LDB + lam * 8;

  auto stageA = [&](int tt, int kap) {
    ushort* d = lds + (tt & 1) * 32768 + kap * 8192 + tid * 8;
    const ushort* s = aG + tt * 64 + kap * 32;
    gload_lds16(s, d);
    gload_lds16(s + (size_t)128 * LDA, d + 4096);
  };
  auto stageB = [&](int tt, int kap) {
    ushort* d = lds + (tt & 1) * 32768 + 16384 + kap * 8192 + tid * 8;
    const ushort* s = bG + tt * 64 + kap * 32;
    gload_lds16(s, d);
    gload_lds16(s + (size_t)128 * LDB, d + 4096);
  };

  // ---- fragment read offsets (ushort units within a slot) ----
  const int sig = fq ^ ((fr >> 1) & 3);  // phys 16B slot
  const int aOff = wr * 4096 + fr * 32 + sig * 8;
  const int bOff = 16384 + wc * 2048 + fr * 32 + sig * 8;

  auto mfma16 = [&](const bf16x8 av[4], const bf16x8 bv[4], int mh) {
    __builtin_amdgcn_s_setprio(1);
    #pragma unroll
    for (int mm = 0; mm < 4; ++mm)
      #pragma unroll
      for (int n = 0; n < 4; ++n)
        acc[mh * 4 + mm][n] =
            __builtin_amdgcn_mfma_f32_16x16x32_bf16(av[mm], bv[n], acc[mh * 4 + mm][n], 0, 0, 0);
    __builtin_amdgcn_s_setprio(0);
  };

  // ---- prologue: stage tile 0 fully (order Ak0,Bk0,Ak1,Bk1) ----
  stageA(0, 0); stageB(0, 0); stageA(0, 1); stageB(0, 1);
  wait_vm<4>();  // Ak0,Bk0 landed
  hard_barrier();

  for (int t = 0; t < NT; ++t) {
    const ushort* sb = lds + (t & 1) * 32768;
    const bool pre = (t + 1 < NT);
    bf16x8 av[4], bv[4];

    // P0: ks0, mh0 -- reads guaranteed by prev P3 vmcnt(4)+barrier (or prologue)
    #pragma unroll
    for (int mm = 0; mm < 4; ++mm) av[mm] = *(const bf16x8*)(sb + aOff + mm * 512);
    #pragma unroll
    for (int n = 0; n < 4; ++n) bv[n] = *(const bf16x8*)(sb + bOff + n * 512);
    if (pre) stageA(t + 1, 0);
    hard_barrier();
    mfma16(av, bv, 0);

    // P1: ks0, mh1 (bv held); vmcnt guards next phase's ks1 reads
    #pragma unroll
    for (int mm = 0; mm < 4; ++mm) av[mm] = *(const bf16x8*)(sb + aOff + 2048 + mm * 512);
    if (pre) { stageB(t + 1, 0); wait_vm<4>(); } else { wait_vm<0>(); }
    hard_barrier();
    mfma16(av, bv, 1);

    // P2: ks1, mh0
    #pragma unroll
    for (int mm = 0; mm < 4; ++mm) av[mm] = *(const bf16x8*)(sb + 8192 + aOff + mm * 512);
    #pragma unroll
    for (int n = 0; n < 4; ++n) bv[n] = *(const bf16x8*)(sb + 8192 + bOff + n * 512);
    if (pre) stageA(t + 1, 1);
    hard_barrier();
    mfma16(av, bv, 0);

    // P3: ks1, mh1; vmcnt guards next tile's P0/P1 reads
    #pragma unroll
    for (int mm = 0; mm < 4; ++mm) av[mm] = *(const bf16x8*)(sb + 8192 + aOff + 2048 + mm * 512);
    if (pre) { stageB(t + 1, 1); wait_vm<4>(); }
    hard_barrier();
    mfma16(av, bv, 1);
  }
}

__device__ __forceinline__ void swz_grid(int nx, int& bx, int& by) {
  const int bid = blockIdx.x;
  const int nwg = gridDim.x;
  const int cpx = nwg >> 3;  // grid sizes are multiples of 8
  const int swz = (bid & 7) * cpx + (bid >> 3);
  by = swz / nx;
  bx = swz - by * nx;
}

// ---------- kernel 1: qkv = x @ Wqkv, elu+1 on q,k cols, bf16 out ----------
__global__ __launch_bounds__(512, 1) void gemm_qkv_kernel(const ushort* __restrict__ xb,
                                                          const ushort* __restrict__ wt,
                                                          ushort* __restrict__ qkv) {
  __shared__ ushort lds[65536];  // 128 KiB
  f32x4 acc[8][4] = {};
  int bx, by;
  swz_grid(64, bx, by);
  const int row0 = bx * 256;
  const int col0 = by * 256;
  gemm_core8<1024, 1024, 16>(xb, wt, row0, col0, acc, lds);
  const int l = threadIdx.x & 63;
  const int wid = threadIdx.x >> 6;
  const int wr = wid >> 2, wc = wid & 3;
  const int fr = l & 15, fq = l >> 4;
  #pragma unroll
  for (int m = 0; m < 8; ++m) {
    #pragma unroll
    for (int n = 0; n < 4; ++n) {
      const int c = col0 + wc * 64 + n * 16 + fr;
      #pragma unroll
      for (int j = 0; j < 4; ++j) {
        const int r = row0 + wr * 128 + m * 16 + fq * 4 + j;
        float v = acc[m][n][j];
        if (c < 1024) v = (v > 0.f) ? (v + 1.f) : __expf(v);  // elu(v)+1
        qkv[(size_t)r * 1536 + c] = f2bf(v);
      }
    }
  }
}

// ---------- kernel 2: context partials ----------
__global__ __launch_bounds__(256) void ctx_kernel(const ushort* __restrict__ qkv,
                                                  float* __restrict__ part) {
  const int bh = blockIdx.x;     // 0..31
  const int split = blockIdx.y;  // 0..15
  const int b = bh >> 3, h = bh & 7;
  const int t = threadIdx.x;
  const int d0 = (t >> 4) * 4;
  const int e0 = (t & 15) * 4;
  __shared__ ushort ks[64][64];
  __shared__ ushort vs[64][64];
  float acc[4][4] = {};
  const int rowBase = b * 4096 + split * 256;
  for (int chunk = 0; chunk < 256; chunk += 64) {
    __syncthreads();
    #pragma unroll
    for (int p = 0; p < 2; ++p) {
      const int r = (t >> 3) + p * 32;
      const int c = (t & 7) * 8;
      const ushort* src = qkv + (size_t)(rowBase + chunk + r) * 1536;
      *(uint4*)&ks[r][c] = *(const uint4*)(src + 512 + h * 64 + c);
      *(uint4*)&vs[r][c] = *(const uint4*)(src + 1024 + h * 64 + c);
    }
    __syncthreads();
    for (int r = 0; r < 64; ++r) {
      ushort4 ku = *(const ushort4*)&ks[r][d0];
      ushort4 vu = *(const ushort4*)&vs[r][e0];
      float kk[4] = {bf2f(ku.x), bf2f(ku.y), bf2f(ku.z), bf2f(ku.w)};
      float vv[4] = {bf2f(vu.x), bf2f(vu.y), bf2f(vu.z), bf2f(vu.w)};
      #pragma unroll
      for (int i = 0; i < 4; ++i)
        #pragma unroll
        for (int j = 0; j < 4; ++j)
          acc[i][j] += kk[i] * vv[j];
    }
  }
  float* dst = part + ((size_t)split * 32 + bh) * 4096;
  #pragma unroll
  for (int i = 0; i < 4; ++i)
    #pragma unroll
    for (int j = 0; j < 4; ++j)
      dst[(d0 + i) * 64 + (e0 + j)] = acc[i][j];
}

// ---------- kernel 3: reduce partials ----------
__global__ __launch_bounds__(256) void ctx_reduce_kernel(const float* __restrict__ part,
                                                         float* __restrict__ ctx) {
  const int i = blockIdx.x * 256 + threadIdx.x;  // 131072 total
  float s = 0.f;
  #pragma unroll
  for (int sp = 0; sp < 16; ++sp) s += part[(size_t)sp * 131072 + i];
  ctx[i] = s;
}

// ---------- kernel 4: W_eff^T ----------
__global__ __launch_bounds__(256) void weff_kernel(const float* __restrict__ ctx,
                                                   const float* __restrict__ Wout,
                                                   ushort* __restrict__ weff) {
  const int bh = blockIdx.x;  // b*8+h
  const int h = bh & 7;
  const int m0 = blockIdx.y * 128;
  const int t = threadIdx.x;
  __shared__ float cs[64 * 64];
  __shared__ float ws[64][128];
  #pragma unroll
  for (int p = 0; p < 4; ++p) {
    const int idx = p * 1024 + t * 4;
    *(float4*)&cs[idx] = *(const float4*)&ctx[(size_t)bh * 4096 + idx];
  }
  #pragma unroll
  for (int p = 0; p < 8; ++p) {
    const int e = (t >> 5) + p * 8;
    const int c = (t & 31) * 4;
    *(float4*)&ws[e][c] = *(const float4*)&Wout[(size_t)(h * 64 + e) * 1024 + m0 + c];
  }
  __syncthreads();
  const int m = t & 127;
  const int dh = (t >> 7) * 32;
  float acc[32] = {};
  for (int e = 0; e < 64; ++e) {
    const float w = ws[e][m];
    #pragma unroll
    for (int i = 0; i < 32; ++i)
      acc[i] += cs[(dh + i) * 64 + e] * w;
  }
  ushort* dst = weff + ((size_t)(bh >> 3) * 1024 + m0 + m) * 512 + h * 64 + dh;
  #pragma unroll
  for (int i = 0; i < 32; ++i) dst[i] = f2bf(acc[i]);
}

// ---------- kernel 5: out = q @ W_eff^T + b_out (fp32 out) ----------
__global__ __launch_bounds__(512, 1) void gemm_out_kernel(const ushort* __restrict__ qkv,
                                                          const ushort* __restrict__ weff,
                                                          const float* __restrict__ bout,
                                                          float* __restrict__ out) {
  __shared__ ushort lds[65536];  // 128 KiB
  f32x4 acc[8][4] = {};
  int bx, by;
  swz_grid(64, bx, by);
  const int row0 = bx * 256;
  const int col0 = by * 256;
  const int b = row0 >> 12;  // row0 / 4096
  gemm_core8<1536, 512, 8>(qkv, weff + (size_t)b * 1024 * 512, row0, col0, acc, lds);
  const int l = threadIdx.x & 63;
  const int wid = threadIdx.x >> 6;
  const int wr = wid >> 2, wc = wid & 3;
  const int fr = l & 15, fq = l >> 4;
  #pragma unroll
  for (int m = 0; m < 8; ++m) {
    #pragma unroll
    for (int n = 0; n < 4; ++n) {
      const int c = col0 + wc * 64 + n * 16 + fr;
      const float bb = bout[c];
      #pragma unroll
      for (int j = 0; j < 4; ++j) {
        const int r = row0 + wr * 128 + m * 16 + fq * 4 + j;
        out[(size_t)r * 1024 + c] = acc[m][n][j] + bb;
      }
    }
  }
}

extern "C" void kernel_launch(void* const* d_in, const int* in_sizes, int n_in,
                              void* d_out, int out_size, void* d_ws, size_t ws_size,
                              hipStream_t stream) {
  const float* x    = (const float*)d_in[0];
  const float* Wqkv = (const float*)d_in[1];
  const float* Wout = (const float*)d_in[2];
  const float* bout = (const float*)d_in[3];
  float* out = (float*)d_out;
  char* ws = (char*)d_ws;

  // workspace layout (bytes)
  ushort* xb   = (ushort*)(ws);              // 16384*1024*2  = 33554432
  ushort* wt   = (ushort*)(ws + 33554432);   // 1536*1024*2   = 3145728
  ushort* qkv  = (ushort*)(ws + 36700160);   // 16384*1536*2  = 50331648
  float*  part = (float* )(ws + 87031808);   // 16*32*4096*4  = 8388608
  float*  ctx  = (float* )(ws + 95420416);   // 32*4096*4     = 524288
  ushort* weff = (ushort*)(ws + 95944704);   // 4*1024*512*2  = 4194304

  cvt_x_kernel<<<2048, 256, 0, stream>>>((const float4*)x, (ushort4*)xb, 16384 * 1024 / 4);
  transpose_w_kernel<<<dim3(48, 32), dim3(32, 8), 0, stream>>>(Wqkv, wt);
  gemm_qkv_kernel<<<384, 512, 0, stream>>>(xb, wt, qkv);
  ctx_kernel<<<dim3(32, 16), 256, 0, stream>>>(qkv, part);
  ctx_reduce_kernel<<<512, 256, 0, stream>>>(part, ctx);
  weff_kernel<<<dim3(32, 8), 256, 0, stream>>>(ctx, Wout, weff);
  gemm_out_kernel<<<256, 512, 0, stream>>>(qkv, weff, bout, out);
}

// Round 5
// 152.686 us; speedup vs baseline: 1.0213x; 1.0213x over previous
//
#include <hip/hip_runtime.h>
#include <hip/hip_bf16.h>
#include <cstdint>

typedef __attribute__((ext_vector_type(4))) float f32x4;
typedef __attribute__((ext_vector_type(8))) short bf16x8;

__device__ __forceinline__ ushort f2bf(float f) {
  unsigned u = __builtin_bit_cast(unsigned, f);
  u += 0x7fffu + ((u >> 16) & 1u);
  return (ushort)(u >> 16);
}
__device__ __forceinline__ float bf2f(ushort h) {
  unsigned u = ((unsigned)h) << 16;
  return __builtin_bit_cast(float, u);
}

__device__ __forceinline__ void gload_lds16(const ushort* g, ushort* l) {
  __builtin_amdgcn_global_load_lds(
      (const __attribute__((address_space(1))) unsigned int*)g,
      (__attribute__((address_space(3))) unsigned int*)l, 16, 0, 0);
}

__device__ __forceinline__ void hard_barrier() {
  __builtin_amdgcn_sched_barrier(0);
  __builtin_amdgcn_s_barrier();
  __builtin_amdgcn_sched_barrier(0);
}

template <int N>
__device__ __forceinline__ void wait_vm() {
  if constexpr (N == 0) asm volatile("s_waitcnt vmcnt(0)" ::: "memory");
  else if constexpr (N == 6) asm volatile("s_waitcnt vmcnt(6)" ::: "memory");
  else static_assert(N < 0, "unsupported vmcnt");
}

// ---------- kernel 0a: x fp32 -> bf16 ----------
__global__ __launch_bounds__(256) void cvt_x_kernel(const float4* __restrict__ x,
                                                    ushort4* __restrict__ xb, int n4) {
  int stride = gridDim.x * blockDim.x;
  for (int i = blockIdx.x * blockDim.x + threadIdx.x; i < n4; i += stride) {
    float4 f = x[i];
    ushort4 o;
    o.x = f2bf(f.x); o.y = f2bf(f.y); o.z = f2bf(f.z); o.w = f2bf(f.w);
    xb[i] = o;
  }
}

// ---------- kernel 0b: W_qkv [1024][1536] f32 -> Wt [1536][1024] bf16 ----------
__global__ __launch_bounds__(256) void transpose_w_kernel(const float* __restrict__ W,
                                                          ushort* __restrict__ Wt) {
  __shared__ float tile[32][33];
  int n0 = blockIdx.x * 32;
  int k0 = blockIdx.y * 32;
  int tx = threadIdx.x;  // 0..31
  int ty = threadIdx.y;  // 0..7
  #pragma unroll
  for (int p = 0; p < 4; ++p) {
    int k = k0 + ty + p * 8;
    tile[ty + p * 8][tx] = W[(size_t)k * 1536 + n0 + tx];
  }
  __syncthreads();
  #pragma unroll
  for (int p = 0; p < 4; ++p) {
    int n = n0 + ty + p * 8;
    Wt[(size_t)n * 1024 + k0 + tx] = f2bf(tile[tx][ty + p * 8]);
  }
}

// ============================================================================
// m201 deep-stagger 256x256 GEMM core. BK=64, 512 threads = 8 waves (2M x 4N),
// per-wave output 128x64 (MREP=8, NREP=4). LDS = 2 slots x 64KB = 128 KiB.
// Slot layout (ushorts): [Ak0 8192 | Ak1 8192 | Bk0 8192 | Bk1 8192].
// Per K-tile t: 4 phases, quadrant order (mh0,ks0)(mh1,ks0)(mh0,ks1)(mh1,ks1),
// bv(ks) held in regs across the mh pair. Each phase:
//   { ds_read frags (4 or 8); stage one designated half; [vmcnt @ph4];
//     barrier; MFMA16 (setprio); barrier }
// Stage schedule (earliest WAR-legal, certified by prior post-MFMA barrier):
//   ph1: Ak1(t+1)   [pred consumed t-1.ph4, certified by tile-boundary bar]
//   ph2: Bk0(t+2)   [Bk0(t) consumed ph1, certified ph1 post-bar]
//   ph3: Ak0(t+2)   [Ak0(t) consumed ph1+ph2, certified ph2 post-bar]
//   ph4: Bk1(t+2)   [Bk1(t) consumed ph3, certified ph3 post-bar]
// vmcnt(6) at ph4 (3 halves x 2 loads outstanding) guarantees ALL of tile t+1
// landed before its ph1 reads; vmcnt(0) when t+2>=NT (tail). Prologue issues
// 7 halves (tile0 x4, tile1 x3) + vmcnt(6) -> tile0's 8 loads landed.
// Bank swizzle (rule #21, linear gload_lds dest, pre-swizzled global source):
//   phys 16B slot = logical ^ ((row>>1)&3); reads 2-way only (free, m136).
// ============================================================================
template <int LDA, int LDB, int NT>
__device__ __forceinline__ void gemm_core_m201(const ushort* __restrict__ A,
                                               const ushort* __restrict__ Bt,
                                               int row0, int col0, f32x4 acc[8][4],
                                               ushort* lds) {
  const int tid = threadIdx.x;
  const int l = tid & 63;
  const int wid = tid >> 6;
  const int fr = l & 15, fq = l >> 4;
  const int wr = wid >> 2, wc = wid & 3;

  // ---- staging (pre-swizzled global source) ----
  const int srow = tid >> 2;                     // 0..127
  const int lam = (tid & 3) ^ ((tid >> 3) & 3);  // logical 16B slot
  const ushort* aG = A + (size_t)(row0 + srow) * LDA + lam * 8;
  const ushort* bG = Bt + (size_t)(col0 + srow) * LDB + lam * 8;

  auto stageA = [&](int tt, int kap) {
    ushort* d = lds + (tt & 1) * 32768 + kap * 8192 + tid * 8;
    const ushort* s = aG + tt * 64 + kap * 32;
    gload_lds16(s, d);
    gload_lds16(s + (size_t)128 * LDA, d + 4096);
  };
  auto stageB = [&](int tt, int kap) {
    ushort* d = lds + (tt & 1) * 32768 + 16384 + kap * 8192 + tid * 8;
    const ushort* s = bG + tt * 64 + kap * 32;
    gload_lds16(s, d);
    gload_lds16(s + (size_t)128 * LDB, d + 4096);
  };

  // ---- fragment read offsets (ushort units within a slot) ----
  const int sig = fq ^ ((fr >> 1) & 3);  // phys 16B slot
  const int aOff = wr * 4096 + fr * 32 + sig * 8;
  const int bOff = 16384 + wc * 2048 + fr * 32 + sig * 8;

  auto mfma16 = [&](const bf16x8 av[4], const bf16x8 bv[4], int mh) {
    __builtin_amdgcn_s_setprio(1);
    #pragma unroll
    for (int mm = 0; mm < 4; ++mm)
      #pragma unroll
      for (int n = 0; n < 4; ++n)
        acc[mh * 4 + mm][n] =
            __builtin_amdgcn_mfma_f32_16x16x32_bf16(av[mm], bv[n], acc[mh * 4 + mm][n], 0, 0, 0);
    __builtin_amdgcn_s_setprio(0);
  };

  // ---- prologue: 7 halves, issue order fixes the vmcnt arithmetic ----
  stageB(0, 0); stageA(0, 0); stageB(0, 1); stageA(0, 1);
  stageB(1, 0); stageA(1, 0); stageB(1, 1);
  wait_vm<6>();  // 14 loads issued, <=6 outstanding -> tile0's 8 landed
  hard_barrier();

  for (int t = 0; t < NT; ++t) {
    const ushort* sb = lds + (t & 1) * 32768;
    bf16x8 av[4], bv[4];

    // ph1: (mh0, ks0) -- reads Ak0 low + Bk0
    #pragma unroll
    for (int mm = 0; mm < 4; ++mm) av[mm] = *(const bf16x8*)(sb + aOff + mm * 512);
    #pragma unroll
    for (int n = 0; n < 4; ++n) bv[n] = *(const bf16x8*)(sb + bOff + n * 512);
    if (t + 1 < NT) stageA(t + 1, 1);
    hard_barrier();
    mfma16(av, bv, 0);
    hard_barrier();

    // ph2: (mh1, ks0) -- reads Ak0 high; bv held
    #pragma unroll
    for (int mm = 0; mm < 4; ++mm) av[mm] = *(const bf16x8*)(sb + aOff + 2048 + mm * 512);
    if (t + 2 < NT) stageB(t + 2, 0);
    hard_barrier();
    mfma16(av, bv, 1);
    hard_barrier();

    // ph3: (mh0, ks1) -- reads Ak1 low + Bk1
    #pragma unroll
    for (int mm = 0; mm < 4; ++mm) av[mm] = *(const bf16x8*)(sb + 8192 + aOff + mm * 512);
    #pragma unroll
    for (int n = 0; n < 4; ++n) bv[n] = *(const bf16x8*)(sb + 8192 + bOff + n * 512);
    if (t + 2 < NT) stageA(t + 2, 0);
    hard_barrier();
    mfma16(av, bv, 0);
    hard_barrier();

    // ph4: (mh1, ks1) -- reads Ak1 high; bv held
    #pragma unroll
    for (int mm = 0; mm < 4; ++mm) av[mm] = *(const bf16x8*)(sb + 8192 + aOff + 2048 + mm * 512);
    if (t + 2 < NT) { stageB(t + 2, 1); wait_vm<6>(); } else { wait_vm<0>(); }
    hard_barrier();
    mfma16(av, bv, 1);
    hard_barrier();  // tile boundary: certifies Ak1(t) consumed
  }
}

// ---------- kernel 1: qkv = x @ Wqkv, elu+1 on q,k cols, bf16 out ----------
__global__ __launch_bounds__(512, 1) void gemm_qkv_kernel(const ushort* __restrict__ xb,
                                                          const ushort* __restrict__ wt,
                                                          ushort* __restrict__ qkv) {
  __shared__ ushort lds[65536];  // 128 KiB
  f32x4 acc[8][4] = {};
  const int row0 = blockIdx.x * 256;
  const int col0 = blockIdx.y * 256;
  gemm_core_m201<1024, 1024, 16>(xb, wt, row0, col0, acc, lds);
  const int l = threadIdx.x & 63;
  const int wid = threadIdx.x >> 6;
  const int wr = wid >> 2, wc = wid & 3;
  const int fr = l & 15, fq = l >> 4;
  #pragma unroll
  for (int m = 0; m < 8; ++m) {
    #pragma unroll
    for (int n = 0; n < 4; ++n) {
      const int c = col0 + wc * 64 + n * 16 + fr;
      #pragma unroll
      for (int j = 0; j < 4; ++j) {
        const int r = row0 + wr * 128 + m * 16 + fq * 4 + j;
        float v = acc[m][n][j];
        if (c < 1024) v = (v > 0.f) ? (v + 1.f) : __expf(v);  // elu(v)+1
        qkv[(size_t)r * 1536 + c] = f2bf(v);
      }
    }
  }
}

// ---------- kernel 2: context partials ----------
__global__ __launch_bounds__(256) void ctx_kernel(const ushort* __restrict__ qkv,
                                                  float* __restrict__ part) {
  const int bh = blockIdx.x;     // 0..31
  const int split = blockIdx.y;  // 0..15
  const int b = bh >> 3, h = bh & 7;
  const int t = threadIdx.x;
  const int d0 = (t >> 4) * 4;
  const int e0 = (t & 15) * 4;
  __shared__ ushort ks[64][64];
  __shared__ ushort vs[64][64];
  float acc[4][4] = {};
  const int rowBase = b * 4096 + split * 256;
  for (int chunk = 0; chunk < 256; chunk += 64) {
    __syncthreads();
    #pragma unroll
    for (int p = 0; p < 2; ++p) {
      const int r = (t >> 3) + p * 32;
      const int c = (t & 7) * 8;
      const ushort* src = qkv + (size_t)(rowBase + chunk + r) * 1536;
      *(uint4*)&ks[r][c] = *(const uint4*)(src + 512 + h * 64 + c);
      *(uint4*)&vs[r][c] = *(const uint4*)(src + 1024 + h * 64 + c);
    }
    __syncthreads();
    for (int r = 0; r < 64; ++r) {
      ushort4 ku = *(const ushort4*)&ks[r][d0];
      ushort4 vu = *(const ushort4*)&vs[r][e0];
      float kk[4] = {bf2f(ku.x), bf2f(ku.y), bf2f(ku.z), bf2f(ku.w)};
      float vv[4] = {bf2f(vu.x), bf2f(vu.y), bf2f(vu.z), bf2f(vu.w)};
      #pragma unroll
      for (int i = 0; i < 4; ++i)
        #pragma unroll
        for (int j = 0; j < 4; ++j)
          acc[i][j] += kk[i] * vv[j];
    }
  }
  float* dst = part + ((size_t)split * 32 + bh) * 4096;
  #pragma unroll
  for (int i = 0; i < 4; ++i)
    #pragma unroll
    for (int j = 0; j < 4; ++j)
      dst[(d0 + i) * 64 + (e0 + j)] = acc[i][j];
}

// ---------- kernel 3: reduce partials ----------
__global__ __launch_bounds__(256) void ctx_reduce_kernel(const float* __restrict__ part,
                                                         float* __restrict__ ctx) {
  const int i = blockIdx.x * 256 + threadIdx.x;  // 131072 total
  float s = 0.f;
  #pragma unroll
  for (int sp = 0; sp < 16; ++sp) s += part[(size_t)sp * 131072 + i];
  ctx[i] = s;
}

// ---------- kernel 4: W_eff^T ----------
__global__ __launch_bounds__(256) void weff_kernel(const float* __restrict__ ctx,
                                                   const float* __restrict__ Wout,
                                                   ushort* __restrict__ weff) {
  const int bh = blockIdx.x;  // b*8+h
  const int h = bh & 7;
  const int m0 = blockIdx.y * 128;
  const int t = threadIdx.x;
  __shared__ float cs[64 * 64];
  __shared__ float ws[64][128];
  #pragma unroll
  for (int p = 0; p < 4; ++p) {
    const int idx = p * 1024 + t * 4;
    *(float4*)&cs[idx] = *(const float4*)&ctx[(size_t)bh * 4096 + idx];
  }
  #pragma unroll
  for (int p = 0; p < 8; ++p) {
    const int e = (t >> 5) + p * 8;
    const int c = (t & 31) * 4;
    *(float4*)&ws[e][c] = *(const float4*)&Wout[(size_t)(h * 64 + e) * 1024 + m0 + c];
  }
  __syncthreads();
  const int m = t & 127;
  const int dh = (t >> 7) * 32;
  float acc[32] = {};
  for (int e = 0; e < 64; ++e) {
    const float w = ws[e][m];
    #pragma unroll
    for (int i = 0; i < 32; ++i)
      acc[i] += cs[(dh + i) * 64 + e] * w;
  }
  ushort* dst = weff + ((size_t)(bh >> 3) * 1024 + m0 + m) * 512 + h * 64 + dh;
  #pragma unroll
  for (int i = 0; i < 32; ++i) dst[i] = f2bf(acc[i]);
}

// ---------- kernel 5: out = q @ W_eff^T + b_out (fp32 out) ----------
__global__ __launch_bounds__(512, 1) void gemm_out_kernel(const ushort* __restrict__ qkv,
                                                          const ushort* __restrict__ weff,
                                                          const float* __restrict__ bout,
                                                          float* __restrict__ out) {
  __shared__ ushort lds[65536];  // 128 KiB
  f32x4 acc[8][4] = {};
  const int row0 = blockIdx.x * 256;
  const int col0 = blockIdx.y * 256;
  const int b = row0 >> 12;  // row0 / 4096
  gemm_core_m201<1536, 512, 8>(qkv, weff + (size_t)b * 1024 * 512, row0, col0, acc, lds);
  const int l = threadIdx.x & 63;
  const int wid = threadIdx.x >> 6;
  const int wr = wid >> 2, wc = wid & 3;
  const int fr = l & 15, fq = l >> 4;
  #pragma unroll
  for (int m = 0; m < 8; ++m) {
    #pragma unroll
    for (int n = 0; n < 4; ++n) {
      const int c = col0 + wc * 64 + n * 16 + fr;
      const float bb = bout[c];
      #pragma unroll
      for (int j = 0; j < 4; ++j) {
        const int r = row0 + wr * 128 + m * 16 + fq * 4 + j;
        out[(size_t)r * 1024 + c] = acc[m][n][j] + bb;
      }
    }
  }
}

extern "C" void kernel_launch(void* const* d_in, const int* in_sizes, int n_in,
                              void* d_out, int out_size, void* d_ws, size_t ws_size,
                              hipStream_t stream) {
  const float* x    = (const float*)d_in[0];
  const float* Wqkv = (const float*)d_in[1];
  const float* Wout = (const float*)d_in[2];
  const float* bout = (const float*)d_in[3];
  float* out = (float*)d_out;
  char* ws = (char*)d_ws;

  // workspace layout (bytes)
  ushort* xb   = (ushort*)(ws);              // 16384*1024*2  = 33554432
  ushort* wt   = (ushort*)(ws + 33554432);   // 1536*1024*2   = 3145728
  ushort* qkv  = (ushort*)(ws + 36700160);   // 16384*1536*2  = 50331648
  float*  part = (float* )(ws + 87031808);   // 16*32*4096*4  = 8388608
  float*  ctx  = (float* )(ws + 95420416);   // 32*4096*4     = 524288
  ushort* weff = (ushort*)(ws + 95944704);   // 4*1024*512*2  = 4194304

  cvt_x_kernel<<<2048, 256, 0, stream>>>((const float4*)x, (ushort4*)xb, 16384 * 1024 / 4);
  transpose_w_kernel<<<dim3(48, 32), dim3(32, 8), 0, stream>>>(Wqkv, wt);
  gemm_qkv_kernel<<<dim3(64, 6), 512, 0, stream>>>(xb, wt, qkv);
  ctx_kernel<<<dim3(32, 16), 256, 0, stream>>>(qkv, part);
  ctx_reduce_kernel<<<512, 256, 0, stream>>>(part, ctx);
  weff_kernel<<<dim3(32, 8), 256, 0, stream>>>(ctx, Wout, weff);
  gemm_out_kernel<<<dim3(64, 4), 512, 0, stream>>>(qkv, weff, bout, out);
}